// Round 1
// baseline (1382.105 us; speedup 1.0000x reference)
//
#include <hip/hip_runtime.h>
#include <float.h>

#define K_NEI 9
#define M 4096
#define N 65536
#define D 128
#define TM 64            // queries per block
#define TN 64            // bank cols per chunk
#define KC 32            // k-chunk staged per Bs fill
#define SEGS 16
#define SEG_LEN (N / SEGS)     // 4096
#define NCHUNK (SEG_LEN / TN)  // 64

// ---------------------------------------------------------------------------
// Kernel 1: per-row sum of squares (wave per row, float2 per lane, shfl-reduce)
// ---------------------------------------------------------------------------
__global__ void rowsq_kernel(const float* __restrict__ x, float* __restrict__ out,
                             int rows) {
    int wave = (int)((blockIdx.x * blockDim.x + threadIdx.x) >> 6);
    int lane = threadIdx.x & 63;
    if (wave >= rows) return;
    const float2* p = (const float2*)(x + (size_t)wave * D);
    float2 v = p[lane];                       // 64 lanes x 2 floats = 128 = D
    float s = v.x * v.x + v.y * v.y;
#pragma unroll
    for (int off = 32; off > 0; off >>= 1) s += __shfl_down(s, off, 64);
    if (lane == 0) out[wave] = s;
}

// ---------------------------------------------------------------------------
// Kernel 2: fused distance GEMM + per-query top-9 (per bank segment)
// grid = (M/TM) * SEGS blocks of 256 threads (16 tx x 16 ty)
// thread tile: 4 queries (ty) x 4 cols (tx)
// ---------------------------------------------------------------------------
__global__ __launch_bounds__(256, 2)
void knn_main(const float* __restrict__ A, const float* __restrict__ B,
              const float* __restrict__ qsq, const float* __restrict__ bsq,
              float* __restrict__ part) {
    __shared__ __align__(16) float As[TM][D + 4];          // 64 x 132 = 33.8 KB
    __shared__ __align__(16) union SU {
        float Bs[KC][TN + 4];                              // 32 x 68  =  8.7 KB
        float mb[TM / 2][16 * K_NEI];                      // 32 x 144 = 18.4 KB
    } u;

    const int tid = threadIdx.x;
    const int tx = tid & 15, ty = tid >> 4;
    const int bq  = blockIdx.x / SEGS;
    const int seg = blockIdx.x % SEGS;
    const int qbase  = bq * TM;
    const int cbase0 = seg * SEG_LEN;

    // stage A tile (64 queries x 128 dims), coalesced float4
    for (int t = tid; t < TM * (D / 4); t += 256) {
        int r = t >> 5;          // D/4 = 32 float4 per row
        int c4 = t & 31;
        float4 v = *(const float4*)(A + (size_t)(qbase + r) * D + c4 * 4);
        *(float4*)&As[r][c4 * 4] = v;
    }

    float qs[4];
#pragma unroll
    for (int i = 0; i < 4; ++i) qs[i] = qsq[qbase + ty * 4 + i];

    // per-thread sorted (ascending) top-9 per query, kept in registers
    float t9[4][K_NEI];
#pragma unroll
    for (int i = 0; i < 4; ++i)
#pragma unroll
        for (int j = 0; j < K_NEI; ++j) t9[i][j] = FLT_MAX;

    __syncthreads();

#pragma unroll 1
    for (int ch = 0; ch < NCHUNK; ++ch) {
        const int cbase = cbase0 + ch * TN;
        float acc[4][4] = {};

#pragma unroll 1
        for (int kc = 0; kc < D / KC; ++kc) {
            const int kb = kc * KC;
            // stage Bs transposed [k][col]
            for (int t = tid; t < TN * (KC / 4); t += 256) {   // 512 -> 2 iters
                int col = t >> 3;
                int k4 = (t & 7) * 4;
                float4 v = *(const float4*)(B + (size_t)(cbase + col) * D + kb + k4);
                u.Bs[k4 + 0][col] = v.x;
                u.Bs[k4 + 1][col] = v.y;
                u.Bs[k4 + 2][col] = v.z;
                u.Bs[k4 + 3][col] = v.w;
            }
            __syncthreads();
#pragma unroll
            for (int kk = 0; kk < KC; kk += 4) {
                float4 a4[4], b4[4];
#pragma unroll
                for (int i = 0; i < 4; ++i)
                    a4[i] = *(const float4*)&As[ty * 4 + i][kb + kk];
#pragma unroll
                for (int k = 0; k < 4; ++k)
                    b4[k] = *(const float4*)&u.Bs[kk + k][tx * 4];
#pragma unroll
                for (int i = 0; i < 4; ++i) {
                    float av0 = a4[i].x, av1 = a4[i].y, av2 = a4[i].z, av3 = a4[i].w;
                    acc[i][0] += av0 * b4[0].x; acc[i][1] += av0 * b4[0].y;
                    acc[i][2] += av0 * b4[0].z; acc[i][3] += av0 * b4[0].w;
                    acc[i][0] += av1 * b4[1].x; acc[i][1] += av1 * b4[1].y;
                    acc[i][2] += av1 * b4[1].z; acc[i][3] += av1 * b4[1].w;
                    acc[i][0] += av2 * b4[2].x; acc[i][1] += av2 * b4[2].y;
                    acc[i][2] += av2 * b4[2].z; acc[i][3] += av2 * b4[2].w;
                    acc[i][0] += av3 * b4[3].x; acc[i][1] += av3 * b4[3].y;
                    acc[i][2] += av3 * b4[3].z; acc[i][3] += av3 * b4[3].w;
                }
            }
            __syncthreads();
        }

        // distances + top-9 insertion
        float bs[4];
#pragma unroll
        for (int j = 0; j < 4; ++j) bs[j] = bsq[cbase + tx * 4 + j];
#pragma unroll
        for (int i = 0; i < 4; ++i) {
#pragma unroll
            for (int j = 0; j < 4; ++j) {
                float d2 = fmaxf(qs[i] + bs[j] - 2.0f * acc[i][j], 0.0f);
                if (d2 < t9[i][K_NEI - 1]) {
                    t9[i][K_NEI - 1] = d2;
#pragma unroll
                    for (int s = K_NEI - 1; s > 0; --s) {
                        float lo = fminf(t9[i][s - 1], t9[i][s]);
                        float hi = fmaxf(t9[i][s - 1], t9[i][s]);
                        t9[i][s - 1] = lo;
                        t9[i][s] = hi;
                    }
                }
            }
        }
    }

    // block-level merge: 16 threads' top-9 -> segment top-9 per query.
    // Two phases of 32 queries so the merge buffer fits in the Bs union.
#pragma unroll 1
    for (int ph = 0; ph < 2; ++ph) {
        __syncthreads();
        if ((ty >> 3) == ph) {
            int tyl = ty & 7;
#pragma unroll
            for (int i = 0; i < 4; ++i)
#pragma unroll
                for (int j = 0; j < K_NEI; ++j)
                    u.mb[tyl * 4 + i][tx * K_NEI + j] = t9[i][j];
        }
        __syncthreads();
        if (tid < 32) {
            float sel[K_NEI];
#pragma unroll 1
            for (int s = 0; s < K_NEI; ++s) {
                float best = FLT_MAX;
                int bi = 0;
                for (int t = 0; t < 16 * K_NEI; ++t) {
                    float v = u.mb[tid][t];
                    if (v < best) { best = v; bi = t; }
                }
                u.mb[tid][bi] = FLT_MAX;
                sel[s] = best;
            }
            int q = qbase + ph * 32 + tid;
            float* dst = part + ((size_t)q * SEGS + seg) * K_NEI;
#pragma unroll
            for (int s = 0; s < K_NEI; ++s) dst[s] = sel[s];
        }
    }
}

// ---------------------------------------------------------------------------
// Kernel 3: final merge across segments + sqrt + mean
// ---------------------------------------------------------------------------
__global__ void knn_final(const float* __restrict__ part, float* __restrict__ out) {
    __shared__ float v[64][SEGS * K_NEI];   // 64 x 144 = 36.9 KB
    int tid = threadIdx.x;
    int q = blockIdx.x * 64 + tid;
    const float* p = part + (size_t)q * (SEGS * K_NEI);
    for (int t = 0; t < SEGS * K_NEI; ++t) v[tid][t] = p[t];
    float sum = 0.f;
    for (int s = 0; s < K_NEI; ++s) {
        float best = FLT_MAX;
        int bi = 0;
        for (int t = 0; t < SEGS * K_NEI; ++t) {
            float x = v[tid][t];
            if (x < best) { best = x; bi = t; }
        }
        v[tid][bi] = FLT_MAX;
        sum += sqrtf(best);
    }
    out[q] = sum * (1.0f / 9.0f);
}

// ---------------------------------------------------------------------------
extern "C" void kernel_launch(void* const* d_in, const int* in_sizes, int n_in,
                              void* d_out, int out_size, void* d_ws, size_t ws_size,
                              hipStream_t stream) {
    const float* feats = (const float*)d_in[0];   // [M, D]
    const float* bank  = (const float*)d_in[1];   // [N, D]
    float* ws   = (float*)d_ws;
    float* bsq  = ws;                  // N floats
    float* qsq  = ws + N;              // M floats
    float* part = ws + N + M;          // M * SEGS * K_NEI floats (~2.25 MB)
    float* out  = (float*)d_out;

    rowsq_kernel<<<N / 4, 256, 0, stream>>>(bank, bsq, N);
    rowsq_kernel<<<M / 4, 256, 0, stream>>>(feats, qsq, M);
    knn_main<<<(M / TM) * SEGS, 256, 0, stream>>>(feats, bank, qsq, bsq, part);
    knn_final<<<M / 64, 64, 0, stream>>>(part, out);
}

// Round 2
// 374.284 us; speedup vs baseline: 3.6927x; 3.6927x over previous
//
#include <hip/hip_runtime.h>
#include <hip/hip_bf16.h>
#include <float.h>

#define K_NEI 9
#define M 4096
#define N 65536
#define D 128
#define SEGS 16
#define SEG_LEN (N / SEGS)     // 4096 bank rows per segment
#define QB 128                 // queries per block
#define BB 128                 // bank rows per chunk
#define CHUNKS (SEG_LEN / BB)  // 32

typedef __bf16 bf16x8 __attribute__((ext_vector_type(8)));
typedef float floatx4 __attribute__((ext_vector_type(4)));

static __device__ inline floatx4 mfma16(bf16x8 a, bf16x8 b, floatx4 c) {
    return __builtin_amdgcn_mfma_f32_16x16x32_bf16(a, b, c, 0, 0, 0);
}

// async global->LDS, 16B per lane, dest = lds_base + lane*16
#define GL_LDS16(gp, lp)                                                     \
    __builtin_amdgcn_global_load_lds(                                        \
        (const __attribute__((address_space(1))) unsigned int*)(const void*)(gp), \
        (__attribute__((address_space(3))) unsigned int*)(void*)(lp), 16, 0, 0)

// ---------------------------------------------------------------------------
// Kernel 1: fp32 -> bf16 convert + row sum-of-squares (wave per row)
// ---------------------------------------------------------------------------
__global__ void prep_kernel(const float* __restrict__ x,
                            __hip_bfloat16* __restrict__ xb,
                            float* __restrict__ sq, int rows) {
    int wave = (int)((blockIdx.x * blockDim.x + threadIdx.x) >> 6);
    int lane = threadIdx.x & 63;
    if (wave >= rows) return;
    float2 v = ((const float2*)(x + (size_t)wave * D))[lane];
    float s = v.x * v.x + v.y * v.y;
    __hip_bfloat16* dst = xb + (size_t)wave * D + lane * 2;
    dst[0] = __float2bfloat16(v.x);
    dst[1] = __float2bfloat16(v.y);
#pragma unroll
    for (int off = 32; off > 0; off >>= 1) s += __shfl_down(s, off, 64);
    if (lane == 0) sq[wave] = s;
}

// ---------------------------------------------------------------------------
// Kernel 2: MFMA distance GEMM + fused per-query top-9 (per bank segment)
// grid = (M/QB) * SEGS blocks of 256 threads (4 waves).
// wave (qw,bw): queries qw*64..+63 (B operand), banks bw*64..+63 (A operand).
// D layout per 16x16 tile: col(query) = lane&15, row(bank) = (lane>>4)*4 + reg.
// ---------------------------------------------------------------------------
__global__ __launch_bounds__(256, 2)
void knn_main(const __hip_bfloat16* __restrict__ bankbf,
              const __hip_bfloat16* __restrict__ featbf,
              const float* __restrict__ bsqp,
              const float* __restrict__ qsqp,
              float* __restrict__ part) {
    __shared__ __align__(16) union SMEM {
        struct {
            short bt[32 * 512];   // 32 KB: 32 regions (bt 0..7 x ks 0..3) x 64 lanes x 8 bf16
            float bsq[SEG_LEN];   // 16 KB: segment bank norms
            int   thr[QB];        // shared per-query gate (float bits, d2 >= 0)
        };
        float merge[QB][8 * K_NEI];  // 36.9 KB epilogue merge buffer
    } sm;

    const int tid  = threadIdx.x;
    const int lane = tid & 63;
    const int wv   = tid >> 6;
    const int qw   = wv & 1;        // query half of block
    const int bw   = wv >> 1;       // bank half of chunk
    const int bq   = blockIdx.x >> 4;        // SEGS = 16
    const int seg  = blockIdx.x & (SEGS - 1);
    const int qbase  = bq * QB;
    const int cbase0 = seg * SEG_LEN;
    const int l15 = lane & 15, l4 = lane >> 4;

    // stage segment bank norms + init thresholds
    for (int t = tid; t < SEG_LEN / 4; t += 256)
        ((float4*)sm.bsq)[t] = ((const float4*)(bsqp + cbase0))[t];
    if (tid < QB) sm.thr[tid] = __float_as_int(FLT_MAX);

    // query fragments (B operand), cached in registers for the whole block
    bf16x8 qf[4][4];
    float qs4[4];
    int qloc[4];
#pragma unroll
    for (int qt = 0; qt < 4; ++qt) {
        int q = qbase + qw * 64 + qt * 16 + l15;
        qs4[qt] = qsqp[q];
        qloc[qt] = qw * 64 + qt * 16 + l15;
#pragma unroll
        for (int ks = 0; ks < 4; ++ks)
            qf[qt][ks] = *(const bf16x8*)(featbf + (size_t)q * D + ks * 32 + l4 * 8);
    }

    float t9[4][K_NEI];
    float gate[4];
#pragma unroll
    for (int qt = 0; qt < 4; ++qt) {
        gate[qt] = FLT_MAX;
#pragma unroll
        for (int j = 0; j < K_NEI; ++j) t9[qt][j] = FLT_MAX;
    }

#pragma unroll 1
    for (int ch = 0; ch < CHUNKS; ++ch) {
        const int cb = cbase0 + ch * BB;
        __syncthreads();  // all waves done reading previous tile
        // stage bank tile (frag-linear): region rgn=(bt*4+ks), lane's 16B slot
#pragma unroll
        for (int i = 0; i < 8; ++i) {
            int rgn = wv * 8 + i;
            int bt = rgn >> 2, ks = rgn & 3;
            const __hip_bfloat16* g =
                bankbf + (size_t)(cb + bt * 16 + l15) * D + ks * 32 + l4 * 8;
            GL_LDS16(g, &sm.bt[rgn * 512]);
        }
        __syncthreads();  // vmcnt drained -> tile ready

        // refresh gates from shared thresholds (stale-high is safe)
#pragma unroll
        for (int qt = 0; qt < 4; ++qt)
            gate[qt] = fminf(gate[qt], __int_as_float(sm.thr[qloc[qt]]));

        // MFMA: 4 bank-tiles x 4 query-tiles, K = 128 (4 ksteps of 32)
        floatx4 acc[4][4];
#pragma unroll
        for (int bb = 0; bb < 4; ++bb)
#pragma unroll
            for (int qt = 0; qt < 4; ++qt)
                acc[bb][qt] = (floatx4){0.f, 0.f, 0.f, 0.f};
#pragma unroll
        for (int ks = 0; ks < 4; ++ks) {
            bf16x8 af[4];
#pragma unroll
            for (int bb = 0; bb < 4; ++bb)
                af[bb] = *(const bf16x8*)&sm.bt[((bw * 4 + bb) * 4 + ks) * 512 + lane * 8];
#pragma unroll
            for (int bb = 0; bb < 4; ++bb)
#pragma unroll
                for (int qt = 0; qt < 4; ++qt)
                    acc[bb][qt] = mfma16(af[bb], qf[qt][ks], acc[bb][qt]);
        }

        // distances + gated top-9 insertion
#pragma unroll
        for (int bb = 0; bb < 4; ++bb) {
            float4 bqv = *(const float4*)&sm.bsq[ch * BB + (bw * 4 + bb) * 16 + l4 * 4];
#pragma unroll
            for (int qt = 0; qt < 4; ++qt) {
#pragma unroll
                for (int r = 0; r < 4; ++r) {
                    float d2 = fmaxf(
                        fmaf(-2.f, acc[bb][qt][r], qs4[qt] + (&bqv.x)[r]), 0.f);
                    if (d2 < gate[qt]) {
                        t9[qt][K_NEI - 1] = d2;
#pragma unroll
                        for (int s = K_NEI - 1; s > 0; --s) {
                            float lo = fminf(t9[qt][s - 1], t9[qt][s]);
                            float hi = fmaxf(t9[qt][s - 1], t9[qt][s]);
                            t9[qt][s - 1] = lo;
                            t9[qt][s] = hi;
                        }
                        gate[qt] = fminf(gate[qt], t9[qt][K_NEI - 1]);
                    }
                }
            }
        }
        // publish tightened thresholds every 4th chunk
        if ((ch & 3) == 3) {
#pragma unroll
            for (int qt = 0; qt < 4; ++qt)
                atomicMin(&sm.thr[qloc[qt]], __float_as_int(t9[qt][K_NEI - 1]));
        }
    }

    // ---- epilogue: merge 8 streams (bw x l4) per query -> segment top-9 ----
    __syncthreads();
    int sid = bw * 4 + l4;
#pragma unroll
    for (int qt = 0; qt < 4; ++qt)
#pragma unroll
        for (int j = 0; j < K_NEI; ++j)
            sm.merge[qloc[qt]][sid * K_NEI + j] = t9[qt][j];
    __syncthreads();
    if (tid < QB) {
        const float* row = sm.merge[tid];
        int idx[8] = {0, 0, 0, 0, 0, 0, 0, 0};
        float outv[K_NEI];
#pragma unroll 1
        for (int s = 0; s < K_NEI; ++s) {
            float best = FLT_MAX;
            int bi = 0;
#pragma unroll
            for (int l8 = 0; l8 < 8; ++l8) {
                float v = (idx[l8] < K_NEI) ? row[l8 * K_NEI + idx[l8]] : FLT_MAX;
                if (v < best) { best = v; bi = l8; }
            }
#pragma unroll
            for (int l8 = 0; l8 < 8; ++l8) idx[l8] += (l8 == bi) ? 1 : 0;
            outv[s] = best;
        }
        float* dst = part + ((size_t)(qbase + tid) * SEGS + seg) * K_NEI;
#pragma unroll
        for (int s = 0; s < K_NEI; ++s) dst[s] = outv[s];
    }
}

// ---------------------------------------------------------------------------
// Kernel 3: final merge across segments + sqrt + mean
// ---------------------------------------------------------------------------
__global__ void knn_final(const float* __restrict__ part, float* __restrict__ out) {
    __shared__ float v[64][SEGS * K_NEI];   // 36.9 KB
    int tid = threadIdx.x;
    int q = blockIdx.x * 64 + tid;
    const float* p = part + (size_t)q * (SEGS * K_NEI);
    for (int t = 0; t < SEGS * K_NEI; ++t) v[tid][t] = p[t];
    float sum = 0.f;
    for (int s = 0; s < K_NEI; ++s) {
        float best = FLT_MAX;
        int bi = 0;
        for (int t = 0; t < SEGS * K_NEI; ++t) {
            float x = v[tid][t];
            if (x < best) { best = x; bi = t; }
        }
        v[tid][bi] = FLT_MAX;
        sum += sqrtf(fmaxf(best, 0.f));
    }
    out[q] = sum * (1.0f / 9.0f);
}

// ---------------------------------------------------------------------------
extern "C" void kernel_launch(void* const* d_in, const int* in_sizes, int n_in,
                              void* d_out, int out_size, void* d_ws, size_t ws_size,
                              hipStream_t stream) {
    const float* feats = (const float*)d_in[0];   // [M, D]
    const float* bank  = (const float*)d_in[1];   // [N, D]

    char* w = (char*)d_ws;
    __hip_bfloat16* bankbf = (__hip_bfloat16*)w;                       // 16 MB
    __hip_bfloat16* featbf = (__hip_bfloat16*)(w + (size_t)N * D * 2); // 1 MB
    float* bsqp = (float*)(w + (size_t)(N + M) * D * 2);               // 256 KB
    float* qsqp = bsqp + N;                                            // 16 KB
    float* part = qsqp + M;                                            // 2.25 MB
    float* out  = (float*)d_out;

    prep_kernel<<<N / 4, 256, 0, stream>>>(bank, bankbf, bsqp, N);
    prep_kernel<<<M / 4, 256, 0, stream>>>(feats, featbf, qsqp, M);
    knn_main<<<(M / QB) * SEGS, 256, 0, stream>>>(bankbf, featbf, bsqp, qsqp, part);
    knn_final<<<M / 64, 64, 0, stream>>>(part, out);
}